// Round 3
// baseline (65.534 us; speedup 1.0000x reference)
//
#include <hip/hip_runtime.h>

// YOLOv1 loss, forward only. preds/targets: (16384,7,7,30) f32 -> scalar f32.
//   coo=(T4>0), noo=(T4==0)
//   noobj   = noo * ((P4-T4)^2 + (P9-T9)^2)
//   iou_b   = IoU(pred box b, pred box 0)   (reference quirk: tbox = pred box 0)
//   idx     = argmax(iou)  [np: first max; NaN acts as max]
//   loss += coo*((P[5i+4]-max_iou)^2 + 0.5*P[5(1-i)+4]^2) + 0.5*noobj
// total = sum / 16384.  (loc_loss and class_loss are exactly 0.)
//
// R2: COMPACT LDS staging. R1 showed runtime independent of HBM traffic
// (L3-resident replays still 78us) -> latency-bound at 17% occupancy.
// Stage only ch0..9 of each array: 2 cells = 15 float4; on r = j%15:
//   r in {0,1,8,9}: keep whole float4, slot = r<3 ? r : r-5
//   r == 2: keep .xy (ch8,9 of cell0)  -> lo half of slot 2
//   r == 7: keep .zw (ch0,1 of cell1)  -> hi half of slot 2
//   else discard.
// Compact layout: S[10*c + ch], 40B/cell/array -> 20.5KB/block -> ~7 blocks/CU.

#define TILE 256
#define NF4  (TILE * 30 / 4)   // 1920 float4 per array per tile
#define SP4  0                 // preds:   float4 slots [0, 640)
#define ST4  640               // targets: float4 slots [640, 1280)
#define TOFF 2560              // targets float offset (640*4)

__device__ __forceinline__ float cell_loss(const float p[10], float t4, float t9) {
    float coo = (t4 > 0.0f) ? 1.0f : 0.0f;
    float noo = (t4 == 0.0f) ? 1.0f : 0.0f;

    float d4 = p[4] - t4;
    float d9 = p[9] - t9;
    float noo_term = noo * (d4 * d4 + d9 * d9);

    // "target" box for IoU = pred box 0 (reference quirk)
    float lt2x = p[0] / 14.0f - 0.5f * p[2];
    float lt2y = p[1] / 14.0f - 0.5f * p[3];
    float rb2x = p[0] / 14.0f + 0.5f * p[2];
    float rb2y = p[1] / 14.0f + 0.5f * p[3];
    float area2 = (rb2x - lt2x) * (rb2y - lt2y);

    float iou[2];
    #pragma unroll
    for (int b = 0; b < 2; ++b) {
        float x = p[5 * b] / 14.0f;
        float y = p[5 * b + 1] / 14.0f;
        float w = p[5 * b + 2];
        float h = p[5 * b + 3];
        float lt1x = x - 0.5f * w, lt1y = y - 0.5f * h;
        float rb1x = x + 0.5f * w, rb1y = y + 0.5f * h;
        float iltx = fmaxf(lt1x, lt2x), ilty = fmaxf(lt1y, lt2y);
        float irbx = fminf(rb1x, rb2x), irby = fminf(rb1y, rb2y);
        float iwx = fmaxf(irbx - iltx, 0.0f);
        float iwy = fmaxf(irby - ilty, 0.0f);
        float inter = iwx * iwy;
        float area1 = (rb1x - lt1x) * (rb1y - lt1y);
        iou[b] = inter / (area1 + area2 - inter);
    }

    // np.argmax: first occurrence of max; NaN compares as maximum.
    int idx;
    float max_iou;
    if (isnan(iou[0]))      { idx = 0; max_iou = iou[0]; }
    else if (isnan(iou[1])) { idx = 1; max_iou = iou[1]; }
    else                    { idx = (iou[1] > iou[0]) ? 1 : 0;
                              max_iou = fmaxf(iou[0], iou[1]); }

    float resp4  = p[5 * idx + 4];
    float nresp4 = p[5 * (1 - idx) + 4];
    float cdiff  = resp4 - max_iou;
    return coo * (cdiff * cdiff + 0.5f * nresp4 * nresp4) + 0.5f * noo_term;
}

__global__ __launch_bounds__(256) void yolo_loss_kernel(
    const float* __restrict__ preds,
    const float* __restrict__ targets,
    float* __restrict__ out,
    int ncells)
{
    __shared__ float4 smem4[1280];       // [0,640) preds compact, [640,1280) targets compact
    __shared__ float  warp_sums[4];
    float*  S  = reinterpret_cast<float*>(smem4);
    float2* S2 = reinterpret_cast<float2*>(smem4);

    const int tid = threadIdx.x;
    const long tile0 = (long)blockIdx.x * TILE;
    float contrib = 0.0f;

    if (tile0 + TILE <= ncells) {
        // ---- staging: coalesced float4 stream -> compact ch0..9 layout ----
        const float4* gp = reinterpret_cast<const float4*>(preds + tile0 * 30);
        const float4* gt = reinterpret_cast<const float4*>(targets + tile0 * 30);

        #pragma unroll
        for (int k = 0; k < 8; ++k) {
            int j = tid + 256 * k;
            if (j < NF4) {
                float4 pv = gp[j];
                float4 tv = gt[j];
                int p15 = j / 15;            // pair index (2 cells per 15 float4)
                int r   = j - p15 * 15;
                int slot = (r < 3) ? r : r - 5;
                int d4   = p15 * 5 + slot;   // compact float4 slot
                bool k128 = (r == 0) | (r == 1) | (r == 8) | (r == 9);
                bool lo = (r == 2), hi = (r == 7);
                if (k128) {
                    smem4[SP4 + d4] = pv;
                    smem4[ST4 + d4] = tv;
                }
                if (lo) {   // ch8,9 of cell0 -> low half of slot 2
                    S2[d4 * 2]              = make_float2(pv.x, pv.y);
                    S2[(ST4 + d4) * 2]      = make_float2(tv.x, tv.y);
                }
                if (hi) {   // ch0,1 of cell1 -> high half of slot 2
                    S2[d4 * 2 + 1]          = make_float2(pv.z, pv.w);
                    S2[(ST4 + d4) * 2 + 1]  = make_float2(tv.z, tv.w);
                }
            }
        }
        __syncthreads();

        // ---- compute: cell c's preds at S[10c..10c+9] (float2-aligned) ----
        float p[10];
        #pragma unroll
        for (int k = 0; k < 5; ++k) {
            float2 q = S2[5 * tid + k];
            p[2 * k]     = q.x;
            p[2 * k + 1] = q.y;
        }
        float t4 = S[TOFF + 10 * tid + 4];
        float t9 = S[TOFF + 10 * tid + 9];
        contrib = cell_loss(p, t4, t9);
    } else {
        // partial tile fallback (unused for 802816 % 256 == 0): direct loads
        long cell = tile0 + tid;
        if (cell < ncells) {
            long base = cell * 30;
            float p[10];
            #pragma unroll
            for (int k = 0; k < 5; ++k) {
                float2 v = *reinterpret_cast<const float2*>(preds + base + 2 * k);
                p[2 * k] = v.x;
                p[2 * k + 1] = v.y;
            }
            contrib = cell_loss(p, targets[base + 4], targets[base + 9]);
        }
        __syncthreads();   // keep barrier count uniform (all threads reach it)
    }

    // wave (64-lane) shuffle reduce
    #pragma unroll
    for (int off = 32; off > 0; off >>= 1)
        contrib += __shfl_down(contrib, off, 64);

    int lane = tid & 63;
    int wid  = tid >> 6;
    if (lane == 0) warp_sums[wid] = contrib;
    __syncthreads();

    if (tid == 0) {
        float s = warp_sums[0] + warp_sums[1] + warp_sums[2] + warp_sums[3];
        atomicAdd(out, s * (1.0f / 16384.0f));
    }
}

extern "C" void kernel_launch(void* const* d_in, const int* in_sizes, int n_in,
                              void* d_out, int out_size, void* d_ws, size_t ws_size,
                              hipStream_t stream) {
    const float* preds   = (const float*)d_in[0];
    const float* targets = (const float*)d_in[1];
    float* out = (float*)d_out;

    int ncells = in_sizes[0] / 30;  // 802816

    hipMemsetAsync(d_out, 0, sizeof(float), stream);

    int grid = (ncells + TILE - 1) / TILE;  // 3136
    yolo_loss_kernel<<<grid, 256, 0, stream>>>(preds, targets, out, ncells);
}

// Round 4
// 38.602 us; speedup vs baseline: 1.6977x; 1.6977x over previous
//
#include <hip/hip_runtime.h>

// YOLOv1 loss, forward only. preds/targets: (16384,7,7,30) f32 -> scalar f32.
//   coo=(T4>0), noo=(T4==0)
//   noobj   = noo * ((P4-T4)^2 + (P9-T9)^2)
//   iou_b   = IoU(pred box b, pred box 0)   (reference quirk: tbox = pred box 0)
//   idx     = argmax(iou)  [np: first max; NaN acts as max]
//   loss += coo*((P[5i+4]-max_iou)^2 + 0.5*P[5(1-i)+4]^2) + 0.5*noobj
// total = sum / 16384.  (loc_loss and class_loss are exactly 0.)
//
// R3: KILL THE SAME-ADDRESS ATOMICS. R0-R2 all plateaued at ~70-85us despite
// wildly different memory structures, and L3-resident replays were just as
// slow -> the invariant is 3136 cross-XCD atomicAdds to one address (~20ns
// each serialized = the whole runtime). Now: blocks store partial sums to
// d_ws[bid] (plain store), tiny second kernel reduces 3136 floats -> d_out.

#define TILE 256
#define NF4  (TILE * 30 / 4)   // 1920 float4 per array per tile
#define SP4  0                 // preds:   float4 slots [0, 640)
#define ST4  640               // targets: float4 slots [640, 1280)
#define TOFF 2560              // targets float offset (640*4)

__device__ __forceinline__ float cell_loss(const float p[10], float t4, float t9) {
    float coo = (t4 > 0.0f) ? 1.0f : 0.0f;
    float noo = (t4 == 0.0f) ? 1.0f : 0.0f;

    float d4 = p[4] - t4;
    float d9 = p[9] - t9;
    float noo_term = noo * (d4 * d4 + d9 * d9);

    // "target" box for IoU = pred box 0 (reference quirk)
    float lt2x = p[0] / 14.0f - 0.5f * p[2];
    float lt2y = p[1] / 14.0f - 0.5f * p[3];
    float rb2x = p[0] / 14.0f + 0.5f * p[2];
    float rb2y = p[1] / 14.0f + 0.5f * p[3];
    float area2 = (rb2x - lt2x) * (rb2y - lt2y);

    float iou[2];
    #pragma unroll
    for (int b = 0; b < 2; ++b) {
        float x = p[5 * b] / 14.0f;
        float y = p[5 * b + 1] / 14.0f;
        float w = p[5 * b + 2];
        float h = p[5 * b + 3];
        float lt1x = x - 0.5f * w, lt1y = y - 0.5f * h;
        float rb1x = x + 0.5f * w, rb1y = y + 0.5f * h;
        float iltx = fmaxf(lt1x, lt2x), ilty = fmaxf(lt1y, lt2y);
        float irbx = fminf(rb1x, rb2x), irby = fminf(rb1y, rb2y);
        float iwx = fmaxf(irbx - iltx, 0.0f);
        float iwy = fmaxf(irby - ilty, 0.0f);
        float inter = iwx * iwy;
        float area1 = (rb1x - lt1x) * (rb1y - lt1y);
        iou[b] = inter / (area1 + area2 - inter);
    }

    // np.argmax: first occurrence of max; NaN compares as maximum.
    int idx;
    float max_iou;
    if (isnan(iou[0]))      { idx = 0; max_iou = iou[0]; }
    else if (isnan(iou[1])) { idx = 1; max_iou = iou[1]; }
    else                    { idx = (iou[1] > iou[0]) ? 1 : 0;
                              max_iou = fmaxf(iou[0], iou[1]); }

    float resp4  = p[5 * idx + 4];
    float nresp4 = p[5 * (1 - idx) + 4];
    float cdiff  = resp4 - max_iou;
    return coo * (cdiff * cdiff + 0.5f * nresp4 * nresp4) + 0.5f * noo_term;
}

__global__ __launch_bounds__(256) void yolo_loss_kernel(
    const float* __restrict__ preds,
    const float* __restrict__ targets,
    float* __restrict__ partials,
    int ncells)
{
    __shared__ float4 smem4[1280];       // [0,640) preds compact, [640,1280) targets compact
    __shared__ float  warp_sums[4];
    float*  S  = reinterpret_cast<float*>(smem4);
    float2* S2 = reinterpret_cast<float2*>(smem4);

    const int tid = threadIdx.x;
    const long tile0 = (long)blockIdx.x * TILE;
    float contrib = 0.0f;

    if (tile0 + TILE <= ncells) {
        // ---- staging: coalesced float4 stream -> compact ch0..9 layout ----
        const float4* gp = reinterpret_cast<const float4*>(preds + tile0 * 30);
        const float4* gt = reinterpret_cast<const float4*>(targets + tile0 * 30);

        #pragma unroll
        for (int k = 0; k < 8; ++k) {
            int j = tid + 256 * k;
            if (j < NF4) {
                float4 pv = gp[j];
                float4 tv = gt[j];
                int p15 = j / 15;            // pair index (2 cells per 15 float4)
                int r   = j - p15 * 15;
                int slot = (r < 3) ? r : r - 5;
                int d4   = p15 * 5 + slot;   // compact float4 slot
                bool k128 = (r == 0) | (r == 1) | (r == 8) | (r == 9);
                bool lo = (r == 2), hi = (r == 7);
                if (k128) {
                    smem4[SP4 + d4] = pv;
                    smem4[ST4 + d4] = tv;
                }
                if (lo) {   // ch8,9 of cell0 -> low half of slot 2
                    S2[d4 * 2]              = make_float2(pv.x, pv.y);
                    S2[(ST4 + d4) * 2]      = make_float2(tv.x, tv.y);
                }
                if (hi) {   // ch0,1 of cell1 -> high half of slot 2
                    S2[d4 * 2 + 1]          = make_float2(pv.z, pv.w);
                    S2[(ST4 + d4) * 2 + 1]  = make_float2(tv.z, tv.w);
                }
            }
        }
        __syncthreads();

        // ---- compute: cell c's preds at S[10c..10c+9] (float2-aligned) ----
        float p[10];
        #pragma unroll
        for (int k = 0; k < 5; ++k) {
            float2 q = S2[5 * tid + k];
            p[2 * k]     = q.x;
            p[2 * k + 1] = q.y;
        }
        float t4 = S[TOFF + 10 * tid + 4];
        float t9 = S[TOFF + 10 * tid + 9];
        contrib = cell_loss(p, t4, t9);
    } else {
        // partial tile fallback (unused: 802816 % 256 == 0)
        long cell = tile0 + tid;
        if (cell < ncells) {
            long base = cell * 30;
            float p[10];
            #pragma unroll
            for (int k = 0; k < 5; ++k) {
                float2 v = *reinterpret_cast<const float2*>(preds + base + 2 * k);
                p[2 * k] = v.x;
                p[2 * k + 1] = v.y;
            }
            contrib = cell_loss(p, targets[base + 4], targets[base + 9]);
        }
        __syncthreads();
    }

    // wave (64-lane) shuffle reduce
    #pragma unroll
    for (int off = 32; off > 0; off >>= 1)
        contrib += __shfl_down(contrib, off, 64);

    int lane = tid & 63;
    int wid  = tid >> 6;
    if (lane == 0) warp_sums[wid] = contrib;
    __syncthreads();

    if (tid == 0) {
        partials[blockIdx.x] = warp_sums[0] + warp_sums[1] + warp_sums[2] + warp_sums[3];
    }
}

__global__ __launch_bounds__(256) void yolo_reduce_kernel(
    const float* __restrict__ partials,
    float* __restrict__ out,
    int nparts)
{
    __shared__ float warp_sums[4];
    const int tid = threadIdx.x;

    float s = 0.0f;
    for (int i = tid; i < nparts; i += 256)
        s += partials[i];

    #pragma unroll
    for (int off = 32; off > 0; off >>= 1)
        s += __shfl_down(s, off, 64);

    int lane = tid & 63;
    int wid  = tid >> 6;
    if (lane == 0) warp_sums[wid] = s;
    __syncthreads();

    if (tid == 0) {
        out[0] = (warp_sums[0] + warp_sums[1] + warp_sums[2] + warp_sums[3])
                 * (1.0f / 16384.0f);
    }
}

extern "C" void kernel_launch(void* const* d_in, const int* in_sizes, int n_in,
                              void* d_out, int out_size, void* d_ws, size_t ws_size,
                              hipStream_t stream) {
    const float* preds   = (const float*)d_in[0];
    const float* targets = (const float*)d_in[1];
    float* out = (float*)d_out;
    float* partials = (float*)d_ws;

    int ncells = in_sizes[0] / 30;          // 802816
    int grid = (ncells + TILE - 1) / TILE;  // 3136

    yolo_loss_kernel<<<grid, 256, 0, stream>>>(preds, targets, partials, ncells);
    yolo_reduce_kernel<<<1, 256, 0, stream>>>(partials, out, grid);
}

// Round 5
// 37.245 us; speedup vs baseline: 1.7595x; 1.0364x over previous
//
#include <hip/hip_runtime.h>

// YOLOv1 loss, forward only. preds/targets: (16384,7,7,30) f32 -> scalar f32.
//   coo=(T4>0), noo=(T4==0)
//   noobj   = noo * ((P4-T4)^2 + (P9-T9)^2)
//   iou_b   = IoU(pred box b, pred box 0)   (reference quirk: tbox = pred box 0)
//   idx     = argmax(iou)  [np: first max; NaN acts as max]
//   loss += coo*((P[5i+4]-max_iou)^2 + 0.5*P[5(1-i)+4]^2) + 0.5*noobj
// total = sum / 16384.  (loc_loss and class_loss are exactly 0.)
//
// R4: (a) load ONLY the needed float4 columns (preds r in {0,1,2,7,8,9},
// targets r in {1,2,8,9} per 2-cell pair) -> 64 MB instead of 192 MB of
// L2/L3 traffic; (b) issue all 5 per-thread loads into registers up front
// (R3 had VGPR=36 -> ~2 loads in flight, latency-bound); (c) LDS down to
// 12.3 KB -> up to 8 blocks/CU.
//
// Per pair p (2 cells, 15 float4 each array):
//   preds  r=0 -> slot 5p+0 (c0 ch0-3)     r=1 -> slot 5p+1 (c0 ch4-7)
//          r=2 -> slot 5p+2 lo (c0 ch8,9)  r=7 -> slot 5p+2 hi (c1 ch0,1)
//          r=8 -> slot 5p+3 (c1 ch2-5)     r=9 -> slot 5p+4 (c1 ch6-9)
//   => cell c's 10 floats contiguous at compact float offset 10c.
//   targets r=1 -> t4_c0 = .x | r=2 -> t9_c0 = .y | r=8 -> t4_c1 = .z
//          | r=9 -> t9_c1 = .w   => Tc[4p + rr] = v[rr]; cell c: Tc[2c],Tc[2c+1]

#define TILE 256   // cells per block; 128 pairs

__device__ __forceinline__ float cell_loss(const float p[10], float t4, float t9) {
    float coo = (t4 > 0.0f) ? 1.0f : 0.0f;
    float noo = (t4 == 0.0f) ? 1.0f : 0.0f;

    float d4 = p[4] - t4;
    float d9 = p[9] - t9;
    float noo_term = noo * (d4 * d4 + d9 * d9);

    // "target" box for IoU = pred box 0 (reference quirk)
    float lt2x = p[0] / 14.0f - 0.5f * p[2];
    float lt2y = p[1] / 14.0f - 0.5f * p[3];
    float rb2x = p[0] / 14.0f + 0.5f * p[2];
    float rb2y = p[1] / 14.0f + 0.5f * p[3];
    float area2 = (rb2x - lt2x) * (rb2y - lt2y);

    float iou[2];
    #pragma unroll
    for (int b = 0; b < 2; ++b) {
        float x = p[5 * b] / 14.0f;
        float y = p[5 * b + 1] / 14.0f;
        float w = p[5 * b + 2];
        float h = p[5 * b + 3];
        float lt1x = x - 0.5f * w, lt1y = y - 0.5f * h;
        float rb1x = x + 0.5f * w, rb1y = y + 0.5f * h;
        float iltx = fmaxf(lt1x, lt2x), ilty = fmaxf(lt1y, lt2y);
        float irbx = fminf(rb1x, rb2x), irby = fminf(rb1y, rb2y);
        float iwx = fmaxf(irbx - iltx, 0.0f);
        float iwy = fmaxf(irby - ilty, 0.0f);
        float inter = iwx * iwy;
        float area1 = (rb1x - lt1x) * (rb1y - lt1y);
        iou[b] = inter / (area1 + area2 - inter);
    }

    // np.argmax: first occurrence of max; NaN compares as maximum.
    int idx;
    float max_iou;
    if (isnan(iou[0]))      { idx = 0; max_iou = iou[0]; }
    else if (isnan(iou[1])) { idx = 1; max_iou = iou[1]; }
    else                    { idx = (iou[1] > iou[0]) ? 1 : 0;
                              max_iou = fmaxf(iou[0], iou[1]); }

    float resp4  = p[5 * idx + 4];
    float nresp4 = p[5 * (1 - idx) + 4];
    float cdiff  = resp4 - max_iou;
    return coo * (cdiff * cdiff + 0.5f * nresp4 * nresp4) + 0.5f * noo_term;
}

__global__ __launch_bounds__(256) void yolo_loss_kernel(
    const float* __restrict__ preds,
    const float* __restrict__ targets,
    float* __restrict__ partials,
    int ncells)
{
    __shared__ float4 smem4[768];        // [0,640) preds compact, [640,768) targets compact
    __shared__ float  warp_sums[4];
    float2* S2 = reinterpret_cast<float2*>(smem4);
    float*  Tc = reinterpret_cast<float*>(smem4 + 640);

    const int tid = threadIdx.x;
    const long tile0 = (long)blockIdx.x * TILE;
    float contrib = 0.0f;

    if (tile0 + TILE <= ncells) {
        const float4* gp = reinterpret_cast<const float4*>(preds + tile0 * 30);
        const float4* gt = reinterpret_cast<const float4*>(targets + tile0 * 30);

        // ---- phase 1: issue ALL loads into registers (5 independent float4) ----
        float4 pv[3];
        #pragma unroll
        for (int k = 0; k < 3; ++k) {          // 768 = 128 pairs * 6 pred columns
            int L = tid + 256 * k;
            int pair = L / 6, rr = L - pair * 6;
            int r = (rr < 3) ? rr : rr + 4;    // {0,1,2,7,8,9}
            pv[k] = gp[pair * 15 + r];
        }
        float4 tv[2];
        #pragma unroll
        for (int k = 0; k < 2; ++k) {          // 512 = 128 pairs * 4 target columns
            int L = tid + 256 * k;
            int pair = L / 4, rr = L & 3;
            int r = (rr < 2) ? rr + 1 : rr + 6; // {1,2,8,9}
            tv[k] = gt[pair * 15 + r];
        }

        // ---- phase 2: compact into LDS ----
        #pragma unroll
        for (int k = 0; k < 3; ++k) {
            int L = tid + 256 * k;
            int pair = L / 6, rr = L - pair * 6;
            if (rr == 2) {                     // c0 ch8,9 -> slot2 lo
                S2[(pair * 5 + 2) * 2] = make_float2(pv[k].x, pv[k].y);
            } else if (rr == 3) {              // (r=7) c1 ch0,1 -> slot2 hi
                S2[(pair * 5 + 2) * 2 + 1] = make_float2(pv[k].z, pv[k].w);
            } else {
                int slot = (rr < 2) ? rr : rr - 1;   // 0,1,3,4
                smem4[pair * 5 + slot] = pv[k];
            }
        }
        #pragma unroll
        for (int k = 0; k < 2; ++k) {
            int L = tid + 256 * k;
            int pair = L / 4, rr = L & 3;
            float v = (rr == 0) ? tv[k].x : (rr == 1) ? tv[k].y
                    : (rr == 2) ? tv[k].z : tv[k].w;
            Tc[pair * 4 + rr] = v;
        }
        __syncthreads();

        // ---- phase 3: compute; cell tid's preds at compact floats [10*tid,10*tid+10) ----
        float p[10];
        #pragma unroll
        for (int k = 0; k < 5; ++k) {
            float2 q = S2[5 * tid + k];
            p[2 * k]     = q.x;
            p[2 * k + 1] = q.y;
        }
        float t4 = Tc[2 * tid];
        float t9 = Tc[2 * tid + 1];
        contrib = cell_loss(p, t4, t9);
    } else {
        // partial tile fallback (unused: 802816 % 256 == 0)
        long cell = tile0 + tid;
        if (cell < ncells) {
            long base = cell * 30;
            float p[10];
            #pragma unroll
            for (int k = 0; k < 5; ++k) {
                float2 v = *reinterpret_cast<const float2*>(preds + base + 2 * k);
                p[2 * k] = v.x;
                p[2 * k + 1] = v.y;
            }
            contrib = cell_loss(p, targets[base + 4], targets[base + 9]);
        }
        __syncthreads();
    }

    // wave (64-lane) shuffle reduce
    #pragma unroll
    for (int off = 32; off > 0; off >>= 1)
        contrib += __shfl_down(contrib, off, 64);

    int lane = tid & 63;
    int wid  = tid >> 6;
    if (lane == 0) warp_sums[wid] = contrib;
    __syncthreads();

    if (tid == 0) {
        partials[blockIdx.x] = warp_sums[0] + warp_sums[1] + warp_sums[2] + warp_sums[3];
    }
}

__global__ __launch_bounds__(256) void yolo_reduce_kernel(
    const float* __restrict__ partials,
    float* __restrict__ out,
    int nparts)
{
    __shared__ float warp_sums[4];
    const int tid = threadIdx.x;

    float s = 0.0f;
    for (int i = tid; i < nparts; i += 256)
        s += partials[i];

    #pragma unroll
    for (int off = 32; off > 0; off >>= 1)
        s += __shfl_down(s, off, 64);

    int lane = tid & 63;
    int wid  = tid >> 6;
    if (lane == 0) warp_sums[wid] = s;
    __syncthreads();

    if (tid == 0) {
        out[0] = (warp_sums[0] + warp_sums[1] + warp_sums[2] + warp_sums[3])
                 * (1.0f / 16384.0f);
    }
}

extern "C" void kernel_launch(void* const* d_in, const int* in_sizes, int n_in,
                              void* d_out, int out_size, void* d_ws, size_t ws_size,
                              hipStream_t stream) {
    const float* preds   = (const float*)d_in[0];
    const float* targets = (const float*)d_in[1];
    float* out = (float*)d_out;
    float* partials = (float*)d_ws;

    int ncells = in_sizes[0] / 30;          // 802816
    int grid = (ncells + TILE - 1) / TILE;  // 3136

    yolo_loss_kernel<<<grid, 256, 0, stream>>>(preds, targets, partials, ncells);
    yolo_reduce_kernel<<<1, 256, 0, stream>>>(partials, out, grid);
}

// Round 6
// 36.478 us; speedup vs baseline: 1.7966x; 1.0210x over previous
//
#include <hip/hip_runtime.h>

// YOLOv1 loss, forward only. preds/targets: (16384,7,7,30) f32 -> scalar f32.
//   coo=(T4>0), noo=(T4==0)
//   noobj   = noo * ((P4-T4)^2 + (P9-T9)^2)
//   iou_b   = IoU(pred box b, pred box 0)   (reference quirk: tbox = pred box 0)
//   idx     = argmax(iou)  [np: first max; NaN acts as max]
//   loss += coo*((P[5i+4]-max_iou)^2 + 0.5*P[5(1-i)+4]^2) + 0.5*noobj
// total = sum / 16384.  (loc_loss and class_loss are exactly 0.)
//
// R5: 2 tiles per block, software-pipelined: stage T0 -> bar -> ISSUE T1
// loads (regs) -> compute T0 -> bar -> write T1 -> bar -> compute T1.
// Grid 1568 (= 6.1 blocks/CU, all resident, no tail). Line-traffic analysis
// says 192 MB of 128B lines is unavoidable (needed-byte gaps < 128B in both
// arrays); this round discriminates latency-bound (drop to ~30us) vs
// L3-line-BW roofline (~37us stays).

#define TILE 256   // cells per tile; 128 pairs
#define NT   2     // tiles per block

__device__ __forceinline__ float cell_loss(const float p[10], float t4, float t9) {
    float coo = (t4 > 0.0f) ? 1.0f : 0.0f;
    float noo = (t4 == 0.0f) ? 1.0f : 0.0f;

    float d4 = p[4] - t4;
    float d9 = p[9] - t9;
    float noo_term = noo * (d4 * d4 + d9 * d9);

    // "target" box for IoU = pred box 0 (reference quirk)
    float lt2x = p[0] / 14.0f - 0.5f * p[2];
    float lt2y = p[1] / 14.0f - 0.5f * p[3];
    float rb2x = p[0] / 14.0f + 0.5f * p[2];
    float rb2y = p[1] / 14.0f + 0.5f * p[3];
    float area2 = (rb2x - lt2x) * (rb2y - lt2y);

    float iou[2];
    #pragma unroll
    for (int b = 0; b < 2; ++b) {
        float x = p[5 * b] / 14.0f;
        float y = p[5 * b + 1] / 14.0f;
        float w = p[5 * b + 2];
        float h = p[5 * b + 3];
        float lt1x = x - 0.5f * w, lt1y = y - 0.5f * h;
        float rb1x = x + 0.5f * w, rb1y = y + 0.5f * h;
        float iltx = fmaxf(lt1x, lt2x), ilty = fmaxf(lt1y, lt2y);
        float irbx = fminf(rb1x, rb2x), irby = fminf(rb1y, rb2y);
        float iwx = fmaxf(irbx - iltx, 0.0f);
        float iwy = fmaxf(irby - ilty, 0.0f);
        float inter = iwx * iwy;
        float area1 = (rb1x - lt1x) * (rb1y - lt1y);
        iou[b] = inter / (area1 + area2 - inter);
    }

    // np.argmax: first occurrence of max; NaN compares as maximum.
    int idx;
    float max_iou;
    if (isnan(iou[0]))      { idx = 0; max_iou = iou[0]; }
    else if (isnan(iou[1])) { idx = 1; max_iou = iou[1]; }
    else                    { idx = (iou[1] > iou[0]) ? 1 : 0;
                              max_iou = fmaxf(iou[0], iou[1]); }

    float resp4  = p[5 * idx + 4];
    float nresp4 = p[5 * (1 - idx) + 4];
    float cdiff  = resp4 - max_iou;
    return coo * (cdiff * cdiff + 0.5f * nresp4 * nresp4) + 0.5f * noo_term;
}

struct TileRegs { float4 pv[3]; float4 tv[2]; };

// issue global loads for one 256-cell tile into registers
__device__ __forceinline__ void issue_tile(const float* __restrict__ preds,
                                           const float* __restrict__ targets,
                                           long tile0, int tid, TileRegs& R) {
    const float4* gp = reinterpret_cast<const float4*>(preds + tile0 * 30);
    const float4* gt = reinterpret_cast<const float4*>(targets + tile0 * 30);
    #pragma unroll
    for (int k = 0; k < 3; ++k) {           // 768 = 128 pairs * 6 pred cols
        int L = tid + 256 * k;
        int pair = L / 6, rr = L - pair * 6;
        int r = (rr < 3) ? rr : rr + 4;     // {0,1,2,7,8,9}
        R.pv[k] = gp[pair * 15 + r];
    }
    #pragma unroll
    for (int k = 0; k < 2; ++k) {           // 512 = 128 pairs * 4 target cols
        int L = tid + 256 * k;
        int pair = L / 4, rr = L & 3;
        int r = (rr < 2) ? rr + 1 : rr + 6; // {1,2,8,9}
        R.tv[k] = gt[pair * 15 + r];
    }
}

// compact registers into LDS:
//   preds: cell c's 10 floats contiguous at float offset 10c
//   targets: Tc[2c]=t4, Tc[2c+1]=t9
__device__ __forceinline__ void write_tile(float4* smem4, float2* S2, float* Tc,
                                           int tid, const TileRegs& R) {
    #pragma unroll
    for (int k = 0; k < 3; ++k) {
        int L = tid + 256 * k;
        int pair = L / 6, rr = L - pair * 6;
        if (rr == 2)      S2[(pair * 5 + 2) * 2]     = make_float2(R.pv[k].x, R.pv[k].y);
        else if (rr == 3) S2[(pair * 5 + 2) * 2 + 1] = make_float2(R.pv[k].z, R.pv[k].w);
        else { int slot = (rr < 2) ? rr : rr - 1; smem4[pair * 5 + slot] = R.pv[k]; }
    }
    #pragma unroll
    for (int k = 0; k < 2; ++k) {
        int L = tid + 256 * k;
        int pair = L / 4, rr = L & 3;
        float v = (rr == 0) ? R.tv[k].x : (rr == 1) ? R.tv[k].y
                : (rr == 2) ? R.tv[k].z : R.tv[k].w;
        Tc[pair * 4 + rr] = v;
    }
}

__device__ __forceinline__ float compute_tile(const float2* S2, const float* Tc, int tid) {
    float p[10];
    #pragma unroll
    for (int k = 0; k < 5; ++k) {
        float2 q = S2[5 * tid + k];
        p[2 * k]     = q.x;
        p[2 * k + 1] = q.y;
    }
    return cell_loss(p, Tc[2 * tid], Tc[2 * tid + 1]);
}

__global__ __launch_bounds__(256) void yolo_loss_kernel(
    const float* __restrict__ preds,
    const float* __restrict__ targets,
    float* __restrict__ partials,
    int ncells)
{
    __shared__ float4 smem4[768];  // [0,640) preds compact, [640,768) targets compact
    __shared__ float  warp_sums[4];
    float2* S2 = reinterpret_cast<float2*>(smem4);
    float*  Tc = reinterpret_cast<float*>(smem4 + 640);

    const int tid = threadIdx.x;
    const long tA = (long)blockIdx.x * (NT * TILE);
    const long tB = tA + TILE;
    float contrib = 0.0f;

    if (tB + TILE <= ncells) {
        TileRegs A, B;
        issue_tile(preds, targets, tA, tid, A);
        write_tile(smem4, S2, Tc, tid, A);
        __syncthreads();
        issue_tile(preds, targets, tB, tid, B);   // prefetch: overlaps compute of A
        contrib = compute_tile(S2, Tc, tid);
        __syncthreads();                          // LDS of A fully consumed
        write_tile(smem4, S2, Tc, tid, B);
        __syncthreads();
        contrib += compute_tile(S2, Tc, tid);
    } else {
        // generic tail fallback (unused: 802816 = 1568 * 512): direct loads
        #pragma unroll
        for (int t = 0; t < NT; ++t) {
            long cell = tA + (long)t * TILE + tid;
            if (cell < ncells) {
                long base = cell * 30;
                float p[10];
                #pragma unroll
                for (int k = 0; k < 5; ++k) {
                    float2 v = *reinterpret_cast<const float2*>(preds + base + 2 * k);
                    p[2 * k] = v.x;
                    p[2 * k + 1] = v.y;
                }
                contrib += cell_loss(p, targets[base + 4], targets[base + 9]);
            }
        }
    }

    // wave (64-lane) shuffle reduce
    #pragma unroll
    for (int off = 32; off > 0; off >>= 1)
        contrib += __shfl_down(contrib, off, 64);

    int lane = tid & 63;
    int wid  = tid >> 6;
    if (lane == 0) warp_sums[wid] = contrib;
    __syncthreads();

    if (tid == 0) {
        partials[blockIdx.x] = warp_sums[0] + warp_sums[1] + warp_sums[2] + warp_sums[3];
    }
}

__global__ __launch_bounds__(256) void yolo_reduce_kernel(
    const float* __restrict__ partials,
    float* __restrict__ out,
    int nparts)
{
    __shared__ float warp_sums[4];
    const int tid = threadIdx.x;

    float s = 0.0f;
    for (int i = tid; i < nparts; i += 256)
        s += partials[i];

    #pragma unroll
    for (int off = 32; off > 0; off >>= 1)
        s += __shfl_down(s, off, 64);

    int lane = tid & 63;
    int wid  = tid >> 6;
    if (lane == 0) warp_sums[wid] = s;
    __syncthreads();

    if (tid == 0) {
        out[0] = (warp_sums[0] + warp_sums[1] + warp_sums[2] + warp_sums[3])
                 * (1.0f / 16384.0f);
    }
}

extern "C" void kernel_launch(void* const* d_in, const int* in_sizes, int n_in,
                              void* d_out, int out_size, void* d_ws, size_t ws_size,
                              hipStream_t stream) {
    const float* preds   = (const float*)d_in[0];
    const float* targets = (const float*)d_in[1];
    float* out = (float*)d_out;
    float* partials = (float*)d_ws;

    int ncells = in_sizes[0] / 30;                       // 802816
    int grid = (ncells + NT * TILE - 1) / (NT * TILE);   // 1568

    yolo_loss_kernel<<<grid, 256, 0, stream>>>(preds, targets, partials, ncells);
    yolo_reduce_kernel<<<1, 256, 0, stream>>>(partials, out, grid);
}